// Round 1
// baseline (1917.957 us; speedup 1.0000x reference)
//
#include <hip/hip_runtime.h>
#include <math.h>

#define KC 8
#define KCHUNK 512

// ---------------- per-pixel channel sum-of-squares ----------------
__global__ __launch_bounds__(256) void sumsq_k(const float* __restrict__ lq,
                                               const float* __restrict__ refdu,
                                               float* __restrict__ S) {
  const float* src = blockIdx.z ? refdu : lq;
  const int n = blockIdx.y;
  const int h = blockIdx.x * 4 + (threadIdx.x >> 6);
  const int w = threadIdx.x & 63;
  const float* p = src + (size_t)n * 1048576 + h * 64 + w;
  float s0 = 0.f, s1 = 0.f, s2 = 0.f, s3 = 0.f;
  #pragma unroll 4
  for (int c = 0; c < 256; c += 4) {
    float x0 = p[(size_t)c * 4096];
    float x1 = p[(size_t)(c + 1) * 4096];
    float x2 = p[(size_t)(c + 2) * 4096];
    float x3 = p[(size_t)(c + 3) * 4096];
    s0 = fmaf(x0, x0, s0); s1 = fmaf(x1, x1, s1);
    s2 = fmaf(x2, x2, s2); s3 = fmaf(x3, x3, s3);
  }
  S[(blockIdx.z * 2 + n) * 4096 + h * 64 + w] = (s0 + s1) + (s2 + s3);
}

// ---------------- 3x3 box-sum -> inverse patch norms ----------------
__global__ __launch_bounds__(256) void norm_k(const float* __restrict__ S,
                                              float* __restrict__ qinv,
                                              float* __restrict__ kinv) {
  int idx = blockIdx.x * 256 + threadIdx.x;   // 0..16383
  int pix = idx & 4095;
  int nn  = (idx >> 12) & 1;
  int arr = idx >> 13;
  int ph = pix >> 6, pw = pix & 63;
  const float* Sp = S + (arr * 2 + nn) * 4096;
  float sum = 0.f;
  #pragma unroll
  for (int dy = -1; dy <= 1; ++dy) {
    int hh = ph + dy;
    if ((unsigned)hh < 64u) {
      const float* r = Sp + hh * 64;
      #pragma unroll
      for (int dx = -1; dx <= 1; ++dx) {
        int ww = pw + dx;
        if ((unsigned)ww < 64u) sum += r[ww];
      }
    }
  }
  float inv = 1.0f / fmaxf(sqrtf(sum), 1e-12f);
  if (arr) kinv[nn * 4096 + pix] = inv;
  else     qinv[nn * 4096 + pix] = inv;
}

// ---------------- f32 GEMM: D[k][j] = sum_c Ref[c][k] * LQ[c][C0+j] ----------------
// grid: (4096/128, ldD/128); block 256; 128x128 tile, 8x8 per thread, K-step 8
__global__ __launch_bounds__(256) void gemm_d(const float* __restrict__ A,
                                              const float* __restrict__ B,
                                              float* __restrict__ D,
                                              int ldD, int C0) {
  __shared__ __align__(16) float As[8][128];
  __shared__ __align__(16) float Bs[8][128];
  const int tid = threadIdx.x;
  const int k0 = blockIdx.x * 128;
  const int j0 = blockIdx.y * 128;
  const int lr = tid >> 5;            // 0..7
  const int lc = (tid & 31) << 2;     // 0..124
  const int ty = tid >> 4;            // 0..15
  const int tx = tid & 15;            // 0..15

  float acc[8][8];
  #pragma unroll
  for (int i = 0; i < 8; ++i)
    #pragma unroll
    for (int j = 0; j < 8; ++j) acc[i][j] = 0.f;

  const int jq = C0 + j0 + lc;
  const bool bok = (jq >= 0) && (jq < 4096);
  const float* Ap = A + k0 + lc;
  const float* Bp = B + jq;

  for (int ct = 0; ct < 256; ct += 8) {
    float4 av = *reinterpret_cast<const float4*>(Ap + (size_t)(ct + lr) * 4096);
    float4 bv = make_float4(0.f, 0.f, 0.f, 0.f);
    if (bok) bv = *reinterpret_cast<const float4*>(Bp + (size_t)(ct + lr) * 4096);
    __syncthreads();
    *reinterpret_cast<float4*>(&As[lr][lc]) = av;
    *reinterpret_cast<float4*>(&Bs[lr][lc]) = bv;
    __syncthreads();
    #pragma unroll
    for (int kc = 0; kc < 8; ++kc) {
      float a[8], b[8];
      *reinterpret_cast<float4*>(&a[0]) = *reinterpret_cast<const float4*>(&As[kc][ty * 8]);
      *reinterpret_cast<float4*>(&a[4]) = *reinterpret_cast<const float4*>(&As[kc][ty * 8 + 4]);
      *reinterpret_cast<float4*>(&b[0]) = *reinterpret_cast<const float4*>(&Bs[kc][tx * 8]);
      *reinterpret_cast<float4*>(&b[4]) = *reinterpret_cast<const float4*>(&Bs[kc][tx * 8 + 4]);
      #pragma unroll
      for (int i = 0; i < 8; ++i)
        #pragma unroll
        for (int j = 0; j < 8; ++j)
          acc[i][j] = fmaf(a[i], b[j], acc[i][j]);
    }
  }
  #pragma unroll
  for (int i = 0; i < 8; ++i) {
    float* Dp = D + (size_t)(k0 + ty * 8 + i) * ldD + j0 + tx * 8;
    *reinterpret_cast<float4*>(Dp)     = *reinterpret_cast<const float4*>(&acc[i][0]);
    *reinterpret_cast<float4*>(Dp + 4) = *reinterpret_cast<const float4*>(&acc[i][4]);
  }
}

// ---------------- 9-tap diagonal sum + max/argmax over a k-chunk ----------------
// grid: (Wq/256, KC); block 256; thread owns one q
__global__ __launch_bounds__(256) void reduce_max(const float* __restrict__ D,
                                                  int ldD, int C0, int Q0,
                                                  const float* __restrict__ kinvn,
                                                  float* __restrict__ chunkv,
                                                  int* __restrict__ chunki,
                                                  int n) {
  __shared__ float sk[KCHUNK];
  const int tid = threadIdx.x;
  const int q = Q0 + blockIdx.x * 256 + tid;
  const int k0 = blockIdx.y * KCHUNK;
  sk[tid] = kinvn[k0 + tid];
  sk[tid + 256] = kinvn[k0 + tid + 256];
  __syncthreads();

  const int qh = q >> 6, qw = q & 63;
  const bool q_up = qh > 0, q_dn = qh < 63, q_lf = qw > 0, q_rt = qw < 63;

  float best = -INFINITY;
  int bidx = k0;
  const float* Dq = D + (q - C0);
  const int step = ldD + 1;

  #pragma unroll 4
  for (int k = k0; k < k0 + KCHUNK; ++k) {
    const int kh = k >> 6, kw = k & 63;
    const bool k_lf = kw > 0, k_rt = kw < 63;
    float rel = 0.f;
    // dy = -1
    if ((kh > 0) && q_up) {
      const float* p = Dq + (size_t)(k - 64) * ldD - 64;
      if (k_lf && q_lf) rel += p[-step];
      rel += p[0];
      if (k_rt && q_rt) rel += p[step];
    }
    // dy = 0
    {
      const float* p = Dq + (size_t)k * ldD;
      if (k_lf && q_lf) rel += p[-step];
      rel += p[0];
      if (k_rt && q_rt) rel += p[step];
    }
    // dy = +1
    if ((kh < 63) && q_dn) {
      const float* p = Dq + (size_t)(k + 64) * ldD + 64;
      if (k_lf && q_lf) rel += p[-step];
      rel += p[0];
      if (k_rt && q_rt) rel += p[step];
    }
    float val = rel * sk[k - k0];
    if (val > best) { best = val; bidx = k; }
  }
  const int oi = (n * KC + blockIdx.y) * 4096 + q;
  chunkv[oi] = best;
  chunki[oi] = bidx;
}

// ---------------- combine chunks: final max/argmax, soft attention out ----------------
__global__ __launch_bounds__(256) void combine_k(const float* __restrict__ chunkv,
                                                 const int* __restrict__ chunki,
                                                 const float* __restrict__ qinv,
                                                 float* __restrict__ out_sa,
                                                 int* __restrict__ maxidx) {
  int t = blockIdx.x * 256 + threadIdx.x;   // 0..8191
  int n = t >> 12, q = t & 4095;
  float best = -INFINITY;
  int bi = 0;
  #pragma unroll
  for (int ch = 0; ch < KC; ++ch) {
    int ii = (n * KC + ch) * 4096 + q;
    float v = chunkv[ii];
    int ix = chunki[ii];
    if (v > best) { best = v; bi = ix; }   // ascending chunks + strict > == first-index tie-break
  }
  maxidx[t] = bi;
  out_sa[t] = best * qinv[t];
}

// ---------------- gather + fold textures ----------------
// out(n,c,y,x) = (1/9) * sum over valid 3x3 covering patches j of
//   ref(n, c, y + s*(mh-jh), x + s*(mw-jw))   [zero if source OOB]
__global__ __launch_bounds__(256) void texture_k(const float* __restrict__ ref,
                                                 const int* __restrict__ maxidx,
                                                 float* __restrict__ outp,
                                                 int sh, int lw, int lh, int lc) {
  int idx = blockIdx.x * 256 + threadIdx.x;
  const int WW = 1 << lw, HH = 1 << lh, CC = 1 << lc;
  const int s = 1 << sh;
  int x = idx & (WW - 1);
  int y = (idx >> lw) & (HH - 1);
  int c = (idx >> (lw + lh)) & (CC - 1);
  int n = idx >> (lw + lh + lc);
  int jh0 = y >> sh, jw0 = x >> sh;
  const int* mi = maxidx + n * 4096;
  float acc = 0.f;
  const float* rb = ref + ((size_t)(n * CC + c) << (lw + lh));
  #pragma unroll
  for (int a = -1; a <= 1; ++a) {
    int jh = jh0 + a;
    if ((unsigned)jh < 64u) {
      #pragma unroll
      for (int b = -1; b <= 1; ++b) {
        int jw = jw0 + b;
        if ((unsigned)jw < 64u) {
          int m = mi[jh * 64 + jw];
          int sy = y + ((m >> 6) - jh) * s;
          int sx = x + ((m & 63) - jw) * s;
          if ((unsigned)sy < (unsigned)HH && (unsigned)sx < (unsigned)WW)
            acc += rb[(sy << lw) + sx];
        }
      }
    }
  }
  outp[idx] = acc * (1.0f / 9.0f);
}

// ---------------- launch ----------------
extern "C" void kernel_launch(void* const* d_in, const int* in_sizes, int n_in,
                              void* d_out, int out_size, void* d_ws, size_t ws_size,
                              hipStream_t stream) {
  const float* lq    = (const float*)d_in[0];
  const float* refdu = (const float*)d_in[1];
  const float* ref0  = (const float*)d_in[2];
  const float* ref1  = (const float*)d_in[3];
  const float* ref2  = (const float*)d_in[4];
  float* out = (float*)d_out;

  // workspace layout (floats/ints, 4B each)
  float* S      = (float*)d_ws;            // 16384
  float* qinv   = S + 16384;               // 8192
  float* kinv   = qinv + 8192;             // 8192
  int*   maxidx = (int*)(kinv + 8192);     // 8192
  float* chunkv = (float*)(maxidx + 8192); // 2*KC*4096 = 65536
  int*   chunki = (int*)(chunkv + 65536);  // 65536
  const size_t aux_bytes = 688128;         // = 172032 * 4, 256B aligned
  float* D = (float*)((char*)d_ws + aux_bytes);

  // pick the largest q-stripe that fits the workspace
  size_t avail = (ws_size > aux_bytes) ? (ws_size - aux_bytes) : 0;
  int Wq = 256;
  const int cands[5] = {4096, 2048, 1024, 512, 256};
  for (int i = 0; i < 5; ++i) {
    size_t need = (size_t)4096 * (size_t)(cands[i] + 256) * 4;
    if (need <= avail) { Wq = cands[i]; break; }
  }
  const int ldD = Wq + 256;

  // norms
  sumsq_k<<<dim3(16, 2, 2), 256, 0, stream>>>(lq, refdu, S);
  norm_k<<<dim3(64), 256, 0, stream>>>(S, qinv, kinv);

  // D GEMM + chunked argmax reduce, per batch, per q-stripe
  for (int n = 0; n < 2; ++n) {
    const float* A = refdu + (size_t)n * 1048576;  // key source
    const float* B = lq    + (size_t)n * 1048576;  // query source
    for (int Q0 = 0; Q0 < 4096; Q0 += Wq) {
      int C0 = Q0 - 128;
      gemm_d<<<dim3(32, ldD / 128), 256, 0, stream>>>(A, B, D, ldD, C0);
      reduce_max<<<dim3(Wq / 256, KC), 256, 0, stream>>>(D, ldD, C0, Q0,
                                                         kinv + n * 4096,
                                                         chunkv, chunki, n);
    }
  }

  // final argmax + soft attention (out[0:8192])
  combine_k<<<dim3(32), 256, 0, stream>>>(chunkv, chunki, qinv, out, maxidx);

  // textures: level 0 (s=1, C=256, 64x64), level 1 (s=2, C=128, 128x128), level 2 (s=4, C=64, 256x256)
  texture_k<<<dim3(2097152 / 256), 256, 0, stream>>>(ref0, maxidx, out + 8192,    0, 6, 6, 8);
  texture_k<<<dim3(4194304 / 256), 256, 0, stream>>>(ref1, maxidx, out + 2105344, 1, 7, 7, 7);
  texture_k<<<dim3(8388608 / 256), 256, 0, stream>>>(ref2, maxidx, out + 6299648, 2, 8, 8, 6);
}

// Round 3
// 649.213 us; speedup vs baseline: 2.9543x; 2.9543x over previous
//
#include <hip/hip_runtime.h>
#include <math.h>

#define KC2 64
#define KCH 64   // 4096 / KC2

struct __attribute__((packed)) f4u { float v[4]; };  // 4B-aligned 4-float load

// ---------------- per-pixel channel sum-of-squares ----------------
__global__ __launch_bounds__(256) void sumsq_k(const float* __restrict__ lq,
                                               const float* __restrict__ refdu,
                                               float* __restrict__ S) {
  const float* src = blockIdx.z ? refdu : lq;
  const int n = blockIdx.y;
  const int h = blockIdx.x * 4 + (threadIdx.x >> 6);
  const int w = threadIdx.x & 63;
  const float* p = src + (size_t)n * 1048576 + h * 64 + w;
  float s0 = 0.f, s1 = 0.f, s2 = 0.f, s3 = 0.f;
  #pragma unroll 4
  for (int c = 0; c < 256; c += 4) {
    float x0 = p[(size_t)c * 4096];
    float x1 = p[(size_t)(c + 1) * 4096];
    float x2 = p[(size_t)(c + 2) * 4096];
    float x3 = p[(size_t)(c + 3) * 4096];
    s0 = fmaf(x0, x0, s0); s1 = fmaf(x1, x1, s1);
    s2 = fmaf(x2, x2, s2); s3 = fmaf(x3, x3, s3);
  }
  S[(blockIdx.z * 2 + n) * 4096 + h * 64 + w] = (s0 + s1) + (s2 + s3);
}

// ---------------- 3x3 box-sum -> inverse patch norms ----------------
__global__ __launch_bounds__(256) void norm_k(const float* __restrict__ S,
                                              float* __restrict__ qinv,
                                              float* __restrict__ kinv) {
  int idx = blockIdx.x * 256 + threadIdx.x;   // 0..16383
  int pix = idx & 4095;
  int nn  = (idx >> 12) & 1;
  int arr = idx >> 13;
  int ph = pix >> 6, pw = pix & 63;
  const float* Sp = S + (arr * 2 + nn) * 4096;
  float sum = 0.f;
  #pragma unroll
  for (int dy = -1; dy <= 1; ++dy) {
    int hh = ph + dy;
    if ((unsigned)hh < 64u) {
      const float* r = Sp + hh * 64;
      #pragma unroll
      for (int dx = -1; dx <= 1; ++dx) {
        int ww = pw + dx;
        if ((unsigned)ww < 64u) sum += r[ww];
      }
    }
  }
  float inv = 1.0f / fmaxf(sqrtf(sum), 1e-12f);
  if (arr) kinv[nn * 4096 + pix] = inv;
  else     qinv[nn * 4096 + pix] = inv;
}

// ---------------- f32 GEMM: D[k][j] = sum_c Ref[c][k] * LQ[c][C0+j] ----------------
__global__ __launch_bounds__(256) void gemm_d(const float* __restrict__ A,
                                              const float* __restrict__ B,
                                              float* __restrict__ D,
                                              int ldD, int C0) {
  __shared__ __align__(16) float As[8][128];
  __shared__ __align__(16) float Bs[8][128];
  const int tid = threadIdx.x;
  const int k0 = blockIdx.x * 128;
  const int j0 = blockIdx.y * 128;
  const int lr = tid >> 5;            // 0..7
  const int lc = (tid & 31) << 2;     // 0..124
  const int ty = tid >> 4;            // 0..15
  const int tx = tid & 15;            // 0..15

  float acc[8][8];
  #pragma unroll
  for (int i = 0; i < 8; ++i)
    #pragma unroll
    for (int j = 0; j < 8; ++j) acc[i][j] = 0.f;

  const int jq = C0 + j0 + lc;
  const bool bok = (jq >= 0) && (jq < 4096);
  const float* Ap = A + k0 + lc;
  const float* Bp = B + jq;

  for (int ct = 0; ct < 256; ct += 8) {
    float4 av = *reinterpret_cast<const float4*>(Ap + (size_t)(ct + lr) * 4096);
    float4 bv = make_float4(0.f, 0.f, 0.f, 0.f);
    if (bok) bv = *reinterpret_cast<const float4*>(Bp + (size_t)(ct + lr) * 4096);
    __syncthreads();
    *reinterpret_cast<float4*>(&As[lr][lc]) = av;
    *reinterpret_cast<float4*>(&Bs[lr][lc]) = bv;
    __syncthreads();
    #pragma unroll
    for (int kc = 0; kc < 8; ++kc) {
      float a[8], b[8];
      *reinterpret_cast<float4*>(&a[0]) = *reinterpret_cast<const float4*>(&As[kc][ty * 8]);
      *reinterpret_cast<float4*>(&a[4]) = *reinterpret_cast<const float4*>(&As[kc][ty * 8 + 4]);
      *reinterpret_cast<float4*>(&b[0]) = *reinterpret_cast<const float4*>(&Bs[kc][tx * 8]);
      *reinterpret_cast<float4*>(&b[4]) = *reinterpret_cast<const float4*>(&Bs[kc][tx * 8 + 4]);
      #pragma unroll
      for (int i = 0; i < 8; ++i)
        #pragma unroll
        for (int j = 0; j < 8; ++j)
          acc[i][j] = fmaf(a[i], b[j], acc[i][j]);
    }
  }
  #pragma unroll
  for (int i = 0; i < 8; ++i) {
    float* Dp = D + (size_t)(k0 + ty * 8 + i) * ldD + j0 + tx * 8;
    *reinterpret_cast<float4*>(Dp)     = *reinterpret_cast<const float4*>(&acc[i][0]);
    *reinterpret_cast<float4*>(Dp + 4) = *reinterpret_cast<const float4*>(&acc[i][4]);
  }
}

// ---------------- 9-tap DIAGONAL sum + max/argmax, 4 q per thread ----------------
// rel(k,q) = sum over valid delta in {0,+-1,+-63,+-64,+-65} of D[k+delta][q+delta]
// grid: (Wq/1024, 64, nz); block 256. Each chunk = one key row (kh uniform).
__global__ __launch_bounds__(256) void reduce_max4(const float* __restrict__ Dbase,
                                                   int ldD, int C0, int Q0,
                                                   const float* __restrict__ kinv,
                                                   float* __restrict__ chunkv,
                                                   int* __restrict__ chunki,
                                                   int n0, long long dstride) {
  __shared__ float sk[KCH];
  const int n = n0 + blockIdx.z;
  const float* D = Dbase + (size_t)blockIdx.z * (size_t)dstride;
  const int k0 = blockIdx.y * KCH;
  const int kh = blockIdx.y;          // KCH==64: chunk spans exactly one key row
  if (threadIdx.x < KCH) sk[threadIdx.x] = kinv[n * 4096 + k0 + threadIdx.x];
  __syncthreads();

  const int q0 = Q0 + (blockIdx.x * 256 + threadIdx.x) * 4;
  const int qh = q0 >> 6;
  const int qw0 = q0 & 63;
  const bool up = (kh > 0) && (qh > 0);
  const bool dn = (kh < 63) && (qh < 63);
  const bool lf_ok = qw0 > 0;     // lane0's dx=-1 tap column valid
  const bool rt_ok = qw0 < 60;    // lane3's dx=+1 tap column valid

  float b0 = -INFINITY, b1 = -INFINITY, b2 = -INFINITY, b3 = -INFINITY;
  int i0 = k0, i1 = k0, i2 = k0, i3 = k0;
  const float* Dq = D + (q0 - C0);
  const int step = ldD + 1;

  #pragma unroll 2
  for (int kk = 0; kk < KCH; ++kk) {
    const float* P = Dq + (size_t)(k0 + kk) * ldD;
    float4 c0 = *reinterpret_cast<const float4*>(P);
    float r0 = c0.x, r1 = c0.y, r2 = c0.z, r3 = c0.w;
    if (up) {
      float4 c = *reinterpret_cast<const float4*>(P - 64 * step);
      r0 += c.x; r1 += c.y; r2 += c.z; r3 += c.w;
    }
    if (dn) {
      float4 c = *reinterpret_cast<const float4*>(P + 64 * step);
      r0 += c.x; r1 += c.y; r2 += c.z; r3 += c.w;
    }
    if (kk > 0) {                       // dx = -1 taps (k-col and q-col both shift -1)
      f4u a = *reinterpret_cast<const f4u*>(P - step);
      r0 += lf_ok ? a.v[0] : 0.f; r1 += a.v[1]; r2 += a.v[2]; r3 += a.v[3];
      if (up) {
        f4u b = *reinterpret_cast<const f4u*>(P - 65 * step);
        r0 += lf_ok ? b.v[0] : 0.f; r1 += b.v[1]; r2 += b.v[2]; r3 += b.v[3];
      }
      if (dn) {
        f4u b = *reinterpret_cast<const f4u*>(P + 63 * step);
        r0 += lf_ok ? b.v[0] : 0.f; r1 += b.v[1]; r2 += b.v[2]; r3 += b.v[3];
      }
    }
    if (kk < 63) {                      // dx = +1 taps
      f4u a = *reinterpret_cast<const f4u*>(P + step);
      r0 += a.v[0]; r1 += a.v[1]; r2 += a.v[2]; r3 += rt_ok ? a.v[3] : 0.f;
      if (up) {
        f4u b = *reinterpret_cast<const f4u*>(P - 63 * step);
        r0 += b.v[0]; r1 += b.v[1]; r2 += b.v[2]; r3 += rt_ok ? b.v[3] : 0.f;
      }
      if (dn) {
        f4u b = *reinterpret_cast<const f4u*>(P + 65 * step);
        r0 += b.v[0]; r1 += b.v[1]; r2 += b.v[2]; r3 += rt_ok ? b.v[3] : 0.f;
      }
    }
    const float s = sk[kk];
    const int k = k0 + kk;
    float v0 = r0 * s, v1 = r1 * s, v2 = r2 * s, v3 = r3 * s;
    if (v0 > b0) { b0 = v0; i0 = k; }
    if (v1 > b1) { b1 = v1; i1 = k; }
    if (v2 > b2) { b2 = v2; i2 = k; }
    if (v3 > b3) { b3 = v3; i3 = k; }
  }
  const int ob = (n * KC2 + blockIdx.y) * 4096 + q0;
  *reinterpret_cast<float4*>(chunkv + ob) = make_float4(b0, b1, b2, b3);
  *reinterpret_cast<int4*>(chunki + ob) = make_int4(i0, i1, i2, i3);
}

// ---------------- combine chunks: final max/argmax, soft attention out ----------------
__global__ __launch_bounds__(256) void combine_k(const float* __restrict__ chunkv,
                                                 const int* __restrict__ chunki,
                                                 const float* __restrict__ qinv,
                                                 float* __restrict__ out_sa,
                                                 int* __restrict__ maxidx) {
  int t = blockIdx.x * 256 + threadIdx.x;   // 0..8191
  int n = t >> 12, q = t & 4095;
  float best = -INFINITY;
  int bi = 0;
  #pragma unroll 8
  for (int ch = 0; ch < KC2; ++ch) {
    int ii = (n * KC2 + ch) * 4096 + q;
    float v = chunkv[ii];
    int ix = chunki[ii];
    if (v > best) { best = v; bi = ix; }   // ascending chunks + strict > == first-index tie-break
  }
  maxidx[t] = bi;
  out_sa[t] = best * qinv[t];
}

// ---------------- gather + fold textures ----------------
__global__ __launch_bounds__(256) void texture_k(const float* __restrict__ ref,
                                                 const int* __restrict__ maxidx,
                                                 float* __restrict__ outp,
                                                 int sh, int lw, int lh, int lc) {
  int idx = blockIdx.x * 256 + threadIdx.x;
  const int WW = 1 << lw, HH = 1 << lh, CC = 1 << lc;
  const int s = 1 << sh;
  int x = idx & (WW - 1);
  int y = (idx >> lw) & (HH - 1);
  int c = (idx >> (lw + lh)) & (CC - 1);
  int n = idx >> (lw + lh + lc);
  int jh0 = y >> sh, jw0 = x >> sh;
  const int* mi = maxidx + n * 4096;
  float acc = 0.f;
  const float* rb = ref + ((size_t)(n * CC + c) << (lw + lh));
  #pragma unroll
  for (int a = -1; a <= 1; ++a) {
    int jh = jh0 + a;
    if ((unsigned)jh < 64u) {
      #pragma unroll
      for (int b = -1; b <= 1; ++b) {
        int jw = jw0 + b;
        if ((unsigned)jw < 64u) {
          int m = mi[jh * 64 + jw];
          int sy = y + ((m >> 6) - jh) * s;
          int sx = x + ((m & 63) - jw) * s;
          if ((unsigned)sy < (unsigned)HH && (unsigned)sx < (unsigned)WW)
            acc += rb[(sy << lw) + sx];
        }
      }
    }
  }
  outp[idx] = acc * (1.0f / 9.0f);
}

// ---------------- launch ----------------
extern "C" void kernel_launch(void* const* d_in, const int* in_sizes, int n_in,
                              void* d_out, int out_size, void* d_ws, size_t ws_size,
                              hipStream_t stream) {
  const float* lq    = (const float*)d_in[0];
  const float* refdu = (const float*)d_in[1];
  const float* ref0  = (const float*)d_in[2];
  const float* ref1  = (const float*)d_in[3];
  const float* ref2  = (const float*)d_in[4];
  float* out = (float*)d_out;

  // workspace layout (floats/ints, 4B each)
  float* S      = (float*)d_ws;              // 16384
  float* qinv   = S + 16384;                 // 8192
  float* kinv   = qinv + 8192;               // 8192
  int*   maxidx = (int*)(kinv + 8192);       // 8192
  float* chunkv = (float*)(maxidx + 8192);   // 2*KC2*4096 = 524288
  int*   chunki = (int*)(chunkv + 524288);   // 524288
  const size_t aux_bytes = (size_t)(16384 + 8192 + 8192 + 8192 + 524288 + 524288) * 4;
  float* D = (float*)((char*)d_ws + aux_bytes);

  size_t avail = (ws_size > aux_bytes) ? (ws_size - aux_bytes) : 0;
  const size_t stripe4096 = (size_t)4096 * 4352 * 4;   // one full-width D, bytes

  // norms
  sumsq_k<<<dim3(16, 2, 2), 256, 0, stream>>>(lq, refdu, S);
  norm_k<<<dim3(64), 256, 0, stream>>>(S, qinv, kinv);

  if (avail >= 2 * stripe4096) {
    // ---- merged path: both batches' full D resident ----
    const int ldD = 4352, C0 = -128;
    const long long dstride = (long long)4096 * 4352;
    for (int n = 0; n < 2; ++n) {
      gemm_d<<<dim3(32, ldD / 128), 256, 0, stream>>>(
          refdu + (size_t)n * 1048576, lq + (size_t)n * 1048576,
          D + (size_t)n * dstride, ldD, C0);
    }
    reduce_max4<<<dim3(4, KC2, 2), 256, 0, stream>>>(D, ldD, C0, 0, kinv,
                                                     chunkv, chunki, 0, dstride);
  } else {
    // ---- stripe fallback ----
    int Wq = 1024;
    const int cands[3] = {4096, 2048, 1024};
    for (int i = 0; i < 3; ++i) {
      size_t need = (size_t)4096 * (size_t)(cands[i] + 256) * 4;
      if (need <= avail) { Wq = cands[i]; break; }
    }
    const int ldD = Wq + 256;
    for (int n = 0; n < 2; ++n) {
      const float* A = refdu + (size_t)n * 1048576;
      const float* B = lq    + (size_t)n * 1048576;
      for (int Q0 = 0; Q0 < 4096; Q0 += Wq) {
        int C0 = Q0 - 128;
        gemm_d<<<dim3(32, ldD / 128), 256, 0, stream>>>(A, B, D, ldD, C0);
        reduce_max4<<<dim3(Wq / 1024, KC2, 1), 256, 0, stream>>>(
            D, ldD, C0, Q0, kinv, chunkv, chunki, n, 0);
      }
    }
  }

  // final argmax + soft attention (out[0:8192])
  combine_k<<<dim3(32), 256, 0, stream>>>(chunkv, chunki, qinv, out, maxidx);

  // textures
  texture_k<<<dim3(2097152 / 256), 256, 0, stream>>>(ref0, maxidx, out + 8192,    0, 6, 6, 8);
  texture_k<<<dim3(4194304 / 256), 256, 0, stream>>>(ref1, maxidx, out + 2105344, 1, 7, 7, 7);
  texture_k<<<dim3(8388608 / 256), 256, 0, stream>>>(ref2, maxidx, out + 6299648, 2, 8, 8, 6);
}

// Round 4
// 605.784 us; speedup vs baseline: 3.1661x; 1.0717x over previous
//
#include <hip/hip_runtime.h>
#include <math.h>

#define KC2 128
#define KCH 32   // 4096 / KC2

struct __attribute__((packed)) f4u { float v[4]; };  // 4B-aligned 4-float load

// ---------------- per-pixel channel sum-of-squares ----------------
__global__ __launch_bounds__(256) void sumsq_k(const float* __restrict__ lq,
                                               const float* __restrict__ refdu,
                                               float* __restrict__ S) {
  const float* src = blockIdx.z ? refdu : lq;
  const int n = blockIdx.y;
  const int h = blockIdx.x * 4 + (threadIdx.x >> 6);
  const int w = threadIdx.x & 63;
  const float* p = src + (size_t)n * 1048576 + h * 64 + w;
  float s0 = 0.f, s1 = 0.f, s2 = 0.f, s3 = 0.f;
  #pragma unroll 4
  for (int c = 0; c < 256; c += 4) {
    float x0 = p[(size_t)c * 4096];
    float x1 = p[(size_t)(c + 1) * 4096];
    float x2 = p[(size_t)(c + 2) * 4096];
    float x3 = p[(size_t)(c + 3) * 4096];
    s0 = fmaf(x0, x0, s0); s1 = fmaf(x1, x1, s1);
    s2 = fmaf(x2, x2, s2); s3 = fmaf(x3, x3, s3);
  }
  S[(blockIdx.z * 2 + n) * 4096 + h * 64 + w] = (s0 + s1) + (s2 + s3);
}

// ---------------- 3x3 box-sum -> inverse patch norms ----------------
__global__ __launch_bounds__(256) void norm_k(const float* __restrict__ S,
                                              float* __restrict__ qinv,
                                              float* __restrict__ kinv) {
  int idx = blockIdx.x * 256 + threadIdx.x;   // 0..16383
  int pix = idx & 4095;
  int nn  = (idx >> 12) & 1;
  int arr = idx >> 13;
  int ph = pix >> 6, pw = pix & 63;
  const float* Sp = S + (arr * 2 + nn) * 4096;
  float sum = 0.f;
  #pragma unroll
  for (int dy = -1; dy <= 1; ++dy) {
    int hh = ph + dy;
    if ((unsigned)hh < 64u) {
      const float* r = Sp + hh * 64;
      #pragma unroll
      for (int dx = -1; dx <= 1; ++dx) {
        int ww = pw + dx;
        if ((unsigned)ww < 64u) sum += r[ww];
      }
    }
  }
  float inv = 1.0f / fmaxf(sqrtf(sum), 1e-12f);
  if (arr) kinv[nn * 4096 + pix] = inv;
  else     qinv[nn * 4096 + pix] = inv;
}

// ---------------- f32 GEMM: D[k][j] = sum_c Ref[c][k] * LQ[c][C0+j] ----------------
__global__ __launch_bounds__(256) void gemm_d(const float* __restrict__ A,
                                              const float* __restrict__ B,
                                              float* __restrict__ D,
                                              int ldD, int C0) {
  __shared__ __align__(16) float As[8][128];
  __shared__ __align__(16) float Bs[8][128];
  const int tid = threadIdx.x;
  const int k0 = blockIdx.x * 128;
  const int j0 = blockIdx.y * 128;
  const int lr = tid >> 5;            // 0..7
  const int lc = (tid & 31) << 2;     // 0..124
  const int ty = tid >> 4;            // 0..15
  const int tx = tid & 15;            // 0..15

  float acc[8][8];
  #pragma unroll
  for (int i = 0; i < 8; ++i)
    #pragma unroll
    for (int j = 0; j < 8; ++j) acc[i][j] = 0.f;

  const int jq = C0 + j0 + lc;
  const bool bok = (jq >= 0) && (jq < 4096);
  const float* Ap = A + k0 + lc;
  const float* Bp = B + jq;

  for (int ct = 0; ct < 256; ct += 8) {
    float4 av = *reinterpret_cast<const float4*>(Ap + (size_t)(ct + lr) * 4096);
    float4 bv = make_float4(0.f, 0.f, 0.f, 0.f);
    if (bok) bv = *reinterpret_cast<const float4*>(Bp + (size_t)(ct + lr) * 4096);
    __syncthreads();
    *reinterpret_cast<float4*>(&As[lr][lc]) = av;
    *reinterpret_cast<float4*>(&Bs[lr][lc]) = bv;
    __syncthreads();
    #pragma unroll
    for (int kc = 0; kc < 8; ++kc) {
      float a[8], b[8];
      *reinterpret_cast<float4*>(&a[0]) = *reinterpret_cast<const float4*>(&As[kc][ty * 8]);
      *reinterpret_cast<float4*>(&a[4]) = *reinterpret_cast<const float4*>(&As[kc][ty * 8 + 4]);
      *reinterpret_cast<float4*>(&b[0]) = *reinterpret_cast<const float4*>(&Bs[kc][tx * 8]);
      *reinterpret_cast<float4*>(&b[4]) = *reinterpret_cast<const float4*>(&Bs[kc][tx * 8 + 4]);
      #pragma unroll
      for (int i = 0; i < 8; ++i)
        #pragma unroll
        for (int j = 0; j < 8; ++j)
          acc[i][j] = fmaf(a[i], b[j], acc[i][j]);
    }
  }
  #pragma unroll
  for (int i = 0; i < 8; ++i) {
    float* Dp = D + (size_t)(k0 + ty * 8 + i) * ldD + j0 + tx * 8;
    *reinterpret_cast<float4*>(Dp)     = *reinterpret_cast<const float4*>(&acc[i][0]);
    *reinterpret_cast<float4*>(Dp + 4) = *reinterpret_cast<const float4*>(&acc[i][4]);
  }
}

// ---------------- 9-tap DIAGONAL sum + max/argmax, 4 q per thread ----------------
// rel(k,q) = sum over valid delta in {0,+-1,+-63,+-64,+-65} of D[k+delta][q+delta]
// grid: (Wq/1024, KC2, nz); block 256. Chunk = 32 k within one key row (kh uniform).
__global__ __launch_bounds__(256) void reduce_max4(const float* __restrict__ Dbase,
                                                   int ldD, int C0, int Q0,
                                                   const float* __restrict__ kinv,
                                                   float* __restrict__ chunkv,
                                                   int* __restrict__ chunki,
                                                   int n0, long long dstride) {
  __shared__ float sk[KCH];
  const int n = n0 + blockIdx.z;
  const float* D = Dbase + (size_t)blockIdx.z * (size_t)dstride;
  const int k0 = blockIdx.y * KCH;
  const int kh = k0 >> 6;
  const int kwb = k0 & 63;            // 0 or 32
  if (threadIdx.x < KCH) sk[threadIdx.x] = kinv[n * 4096 + k0 + threadIdx.x];
  __syncthreads();

  const int q0 = Q0 + (blockIdx.x * 256 + threadIdx.x) * 4;
  const int qh = q0 >> 6;
  const int qw0 = q0 & 63;
  const bool up = (kh > 0) && (qh > 0);
  const bool dn = (kh < 63) && (qh < 63);
  const bool lf_ok = qw0 > 0;     // lane0's dx=-1 tap column valid
  const bool rt_ok = qw0 < 60;    // lane3's dx=+1 tap column valid

  float b0 = -INFINITY, b1 = -INFINITY, b2 = -INFINITY, b3 = -INFINITY;
  int i0 = k0, i1 = k0, i2 = k0, i3 = k0;
  const float* Dq = D + (q0 - C0);
  const int step = ldD + 1;

  #pragma unroll 4
  for (int kk = 0; kk < KCH; ++kk) {
    const int kw = kwb + kk;
    const float* P = Dq + (size_t)(k0 + kk) * ldD;
    float4 c0 = *reinterpret_cast<const float4*>(P);
    float r0 = c0.x, r1 = c0.y, r2 = c0.z, r3 = c0.w;
    if (up) {
      float4 c = *reinterpret_cast<const float4*>(P - 64 * step);
      r0 += c.x; r1 += c.y; r2 += c.z; r3 += c.w;
    }
    if (dn) {
      float4 c = *reinterpret_cast<const float4*>(P + 64 * step);
      r0 += c.x; r1 += c.y; r2 += c.z; r3 += c.w;
    }
    if (kw > 0) {                       // dx = -1 taps (k and q columns both shift -1)
      f4u a = *reinterpret_cast<const f4u*>(P - step);
      r0 += lf_ok ? a.v[0] : 0.f; r1 += a.v[1]; r2 += a.v[2]; r3 += a.v[3];
      if (up) {
        f4u b = *reinterpret_cast<const f4u*>(P - 65 * step);
        r0 += lf_ok ? b.v[0] : 0.f; r1 += b.v[1]; r2 += b.v[2]; r3 += b.v[3];
      }
      if (dn) {
        f4u b = *reinterpret_cast<const f4u*>(P + 63 * step);
        r0 += lf_ok ? b.v[0] : 0.f; r1 += b.v[1]; r2 += b.v[2]; r3 += b.v[3];
      }
    }
    if (kw < 63) {                      // dx = +1 taps
      f4u a = *reinterpret_cast<const f4u*>(P + step);
      r0 += a.v[0]; r1 += a.v[1]; r2 += a.v[2]; r3 += rt_ok ? a.v[3] : 0.f;
      if (up) {
        f4u b = *reinterpret_cast<const f4u*>(P - 63 * step);
        r0 += b.v[0]; r1 += b.v[1]; r2 += b.v[2]; r3 += rt_ok ? b.v[3] : 0.f;
      }
      if (dn) {
        f4u b = *reinterpret_cast<const f4u*>(P + 65 * step);
        r0 += b.v[0]; r1 += b.v[1]; r2 += b.v[2]; r3 += rt_ok ? b.v[3] : 0.f;
      }
    }
    const float s = sk[kk];
    const int k = k0 + kk;
    float v0 = r0 * s, v1 = r1 * s, v2 = r2 * s, v3 = r3 * s;
    if (v0 > b0) { b0 = v0; i0 = k; }
    if (v1 > b1) { b1 = v1; i1 = k; }
    if (v2 > b2) { b2 = v2; i2 = k; }
    if (v3 > b3) { b3 = v3; i3 = k; }
  }
  const int ob = (n * KC2 + blockIdx.y) * 4096 + q0;
  *reinterpret_cast<float4*>(chunkv + ob) = make_float4(b0, b1, b2, b3);
  *reinterpret_cast<int4*>(chunki + ob) = make_int4(i0, i1, i2, i3);
}

// ---------------- combine chunks: final max/argmax, soft attention out ----------------
__global__ __launch_bounds__(256) void combine_k(const float* __restrict__ chunkv,
                                                 const int* __restrict__ chunki,
                                                 const float* __restrict__ qinv,
                                                 float* __restrict__ out_sa,
                                                 int* __restrict__ maxidx) {
  int t = blockIdx.x * 256 + threadIdx.x;   // 0..8191
  int n = t >> 12, q = t & 4095;
  float best = -INFINITY;
  int bi = 0;
  #pragma unroll 8
  for (int ch = 0; ch < KC2; ++ch) {
    int ii = (n * KC2 + ch) * 4096 + q;
    float v = chunkv[ii];
    int ix = chunki[ii];
    if (v > best) { best = v; bi = ix; }   // ascending chunks + strict > == first-index tie-break
  }
  maxidx[t] = bi;
  out_sa[t] = best * qinv[t];
}

// ---------------- gather + fold textures ----------------
__global__ __launch_bounds__(256) void texture_k(const float* __restrict__ ref,
                                                 const int* __restrict__ maxidx,
                                                 float* __restrict__ outp,
                                                 int sh, int lw, int lh, int lc) {
  int idx = blockIdx.x * 256 + threadIdx.x;
  const int WW = 1 << lw, HH = 1 << lh, CC = 1 << lc;
  const int s = 1 << sh;
  int x = idx & (WW - 1);
  int y = (idx >> lw) & (HH - 1);
  int c = (idx >> (lw + lh)) & (CC - 1);
  int n = idx >> (lw + lh + lc);
  int jh0 = y >> sh, jw0 = x >> sh;
  const int* mi = maxidx + n * 4096;
  float acc = 0.f;
  const float* rb = ref + ((size_t)(n * CC + c) << (lw + lh));
  #pragma unroll
  for (int a = -1; a <= 1; ++a) {
    int jh = jh0 + a;
    if ((unsigned)jh < 64u) {
      #pragma unroll
      for (int b = -1; b <= 1; ++b) {
        int jw = jw0 + b;
        if ((unsigned)jw < 64u) {
          int m = mi[jh * 64 + jw];
          int sy = y + ((m >> 6) - jh) * s;
          int sx = x + ((m & 63) - jw) * s;
          if ((unsigned)sy < (unsigned)HH && (unsigned)sx < (unsigned)WW)
            acc += rb[(sy << lw) + sx];
        }
      }
    }
  }
  outp[idx] = acc * (1.0f / 9.0f);
}

// ---------------- launch ----------------
extern "C" void kernel_launch(void* const* d_in, const int* in_sizes, int n_in,
                              void* d_out, int out_size, void* d_ws, size_t ws_size,
                              hipStream_t stream) {
  const float* lq    = (const float*)d_in[0];
  const float* refdu = (const float*)d_in[1];
  const float* ref0  = (const float*)d_in[2];
  const float* ref1  = (const float*)d_in[3];
  const float* ref2  = (const float*)d_in[4];
  float* out = (float*)d_out;

  // workspace layout (floats/ints, 4B each)
  float* S      = (float*)d_ws;               // 16384
  float* qinv   = S + 16384;                  // 8192
  float* kinv   = qinv + 8192;                // 8192
  int*   maxidx = (int*)(kinv + 8192);        // 8192
  float* chunkv = (float*)(maxidx + 8192);    // 2*KC2*4096 = 1048576
  int*   chunki = (int*)(chunkv + 1048576);   // 1048576
  const size_t aux_bytes = (size_t)(16384 + 8192 + 8192 + 8192 + 1048576 + 1048576) * 4;
  float* D = (float*)((char*)d_ws + aux_bytes);

  size_t avail = (ws_size > aux_bytes) ? (ws_size - aux_bytes) : 0;
  const size_t stripe4096 = (size_t)4096 * 4352 * 4;   // one full-width D, bytes

  // norms
  sumsq_k<<<dim3(16, 2, 2), 256, 0, stream>>>(lq, refdu, S);
  norm_k<<<dim3(64), 256, 0, stream>>>(S, qinv, kinv);

  if (avail >= 2 * stripe4096) {
    // ---- merged path: both batches' full D resident ----
    const int ldD = 4352, C0 = -128;
    const long long dstride = (long long)4096 * 4352;
    for (int n = 0; n < 2; ++n) {
      gemm_d<<<dim3(32, ldD / 128), 256, 0, stream>>>(
          refdu + (size_t)n * 1048576, lq + (size_t)n * 1048576,
          D + (size_t)n * dstride, ldD, C0);
    }
    reduce_max4<<<dim3(4, KC2, 2), 256, 0, stream>>>(D, ldD, C0, 0, kinv,
                                                     chunkv, chunki, 0, dstride);
  } else {
    // ---- stripe fallback ----
    int Wq = 1024;
    const int cands[3] = {4096, 2048, 1024};
    for (int i = 0; i < 3; ++i) {
      size_t need = (size_t)4096 * (size_t)(cands[i] + 256) * 4;
      if (need <= avail) { Wq = cands[i]; break; }
    }
    const int ldD = Wq + 256;
    for (int n = 0; n < 2; ++n) {
      const float* A = refdu + (size_t)n * 1048576;
      const float* B = lq    + (size_t)n * 1048576;
      for (int Q0 = 0; Q0 < 4096; Q0 += Wq) {
        int C0 = Q0 - 128;
        gemm_d<<<dim3(32, ldD / 128), 256, 0, stream>>>(A, B, D, ldD, C0);
        reduce_max4<<<dim3(Wq / 1024, KC2, 1), 256, 0, stream>>>(
            D, ldD, C0, Q0, kinv, chunkv, chunki, n, 0);
      }
    }
  }

  // final argmax + soft attention (out[0:8192])
  combine_k<<<dim3(32), 256, 0, stream>>>(chunkv, chunki, qinv, out, maxidx);

  // textures
  texture_k<<<dim3(2097152 / 256), 256, 0, stream>>>(ref0, maxidx, out + 8192,    0, 6, 6, 8);
  texture_k<<<dim3(4194304 / 256), 256, 0, stream>>>(ref1, maxidx, out + 2105344, 1, 7, 7, 7);
  texture_k<<<dim3(8388608 / 256), 256, 0, stream>>>(ref2, maxidx, out + 6299648, 2, 8, 8, 6);
}

// Round 5
// 548.680 us; speedup vs baseline: 3.4956x; 1.1041x over previous
//
#include <hip/hip_runtime.h>
#include <math.h>

#define KC2 128
#define KCH 32   // 4096 / KC2

struct __attribute__((packed)) f4u { float v[4]; };  // 4B-aligned 4-float load

// ---------------- per-pixel channel sum-of-squares ----------------
__global__ __launch_bounds__(256) void sumsq_k(const float* __restrict__ lq,
                                               const float* __restrict__ refdu,
                                               float* __restrict__ S) {
  const float* src = blockIdx.z ? refdu : lq;
  const int n = blockIdx.y;
  const int h = blockIdx.x * 4 + (threadIdx.x >> 6);
  const int w = threadIdx.x & 63;
  const float* p = src + (size_t)n * 1048576 + h * 64 + w;
  float s0 = 0.f, s1 = 0.f, s2 = 0.f, s3 = 0.f;
  #pragma unroll 4
  for (int c = 0; c < 256; c += 4) {
    float x0 = p[(size_t)c * 4096];
    float x1 = p[(size_t)(c + 1) * 4096];
    float x2 = p[(size_t)(c + 2) * 4096];
    float x3 = p[(size_t)(c + 3) * 4096];
    s0 = fmaf(x0, x0, s0); s1 = fmaf(x1, x1, s1);
    s2 = fmaf(x2, x2, s2); s3 = fmaf(x3, x3, s3);
  }
  S[(blockIdx.z * 2 + n) * 4096 + h * 64 + w] = (s0 + s1) + (s2 + s3);
}

// ---------------- 3x3 box-sum -> inverse patch norms ----------------
__global__ __launch_bounds__(256) void norm_k(const float* __restrict__ S,
                                              float* __restrict__ qinv,
                                              float* __restrict__ kinv) {
  int idx = blockIdx.x * 256 + threadIdx.x;   // 0..16383
  int pix = idx & 4095;
  int nn  = (idx >> 12) & 1;
  int arr = idx >> 13;
  int ph = pix >> 6, pw = pix & 63;
  const float* Sp = S + (arr * 2 + nn) * 4096;
  float sum = 0.f;
  #pragma unroll
  for (int dy = -1; dy <= 1; ++dy) {
    int hh = ph + dy;
    if ((unsigned)hh < 64u) {
      const float* r = Sp + hh * 64;
      #pragma unroll
      for (int dx = -1; dx <= 1; ++dx) {
        int ww = pw + dx;
        if ((unsigned)ww < 64u) sum += r[ww];
      }
    }
  }
  float inv = 1.0f / fmaxf(sqrtf(sum), 1e-12f);
  if (arr) kinv[nn * 4096 + pix] = inv;
  else     qinv[nn * 4096 + pix] = inv;
}

// ---------------- f32 GEMM: D[k][j] = sum_c Ref[c][k] * LQ[c][C0+j] ----------------
// grid: (32, ldD/128, nz); block 256; 128x128 tile; 8x8/thread in 4+4 split;
// double-buffered LDS, 1 barrier per K-step; conflict-free LDS access.
__global__ __launch_bounds__(256) void gemm_d(const float* __restrict__ Abase,
                                              const float* __restrict__ Bbase,
                                              float* __restrict__ Dbase,
                                              int ldD, int C0, long long dstride) {
  __shared__ __align__(16) float As[2][8][128];
  __shared__ __align__(16) float Bs[2][8][128];
  const int tid = threadIdx.x;
  const int nz = blockIdx.z;
  const int k0 = blockIdx.x * 128;
  const int j0 = blockIdx.y * 128;
  const float* A = Abase + (size_t)nz * 1048576;
  const float* B = Bbase + (size_t)nz * 1048576;
  float* D = Dbase + (size_t)nz * dstride;

  const int ty = tid >> 4;            // 0..15 -> a rows ty*4, 64+ty*4
  const int tx = tid & 15;            // 0..15 -> b cols tx*4, 64+tx*4
  const int lr = tid >> 5;            // staging row 0..7
  const int lc = (tid & 31) << 2;     // staging col (floats)

  float acc[8][8];
  #pragma unroll
  for (int i = 0; i < 8; ++i)
    #pragma unroll
    for (int j = 0; j < 8; ++j) acc[i][j] = 0.f;

  // fully-OOB halo block-column? (q range [C0+j0, C0+j0+128) outside [0,4096))
  const bool oob = (C0 + j0 < 0) || (C0 + j0 + 128 > 4096);

  if (!oob) {
    const float* Ap = A + k0 + lc;
    const float* Bp = B + (C0 + j0) + lc;

    float4 av = *reinterpret_cast<const float4*>(Ap + (size_t)lr * 4096);
    float4 bv = *reinterpret_cast<const float4*>(Bp + (size_t)lr * 4096);
    *reinterpret_cast<float4*>(&As[0][lr][lc]) = av;
    *reinterpret_cast<float4*>(&Bs[0][lr][lc]) = bv;

    for (int ct = 0; ct < 256; ct += 8) {
      const int buf = (ct >> 3) & 1;
      __syncthreads();
      if (ct + 8 < 256) {
        av = *reinterpret_cast<const float4*>(Ap + (size_t)(ct + 8 + lr) * 4096);
        bv = *reinterpret_cast<const float4*>(Bp + (size_t)(ct + 8 + lr) * 4096);
      }
      #pragma unroll
      for (int kc = 0; kc < 8; ++kc) {
        float a[8], b[8];
        *reinterpret_cast<float4*>(&a[0]) = *reinterpret_cast<const float4*>(&As[buf][kc][ty * 4]);
        *reinterpret_cast<float4*>(&a[4]) = *reinterpret_cast<const float4*>(&As[buf][kc][64 + ty * 4]);
        *reinterpret_cast<float4*>(&b[0]) = *reinterpret_cast<const float4*>(&Bs[buf][kc][tx * 4]);
        *reinterpret_cast<float4*>(&b[4]) = *reinterpret_cast<const float4*>(&Bs[buf][kc][64 + tx * 4]);
        #pragma unroll
        for (int i = 0; i < 8; ++i)
          #pragma unroll
          for (int j = 0; j < 8; ++j)
            acc[i][j] = fmaf(a[i], b[j], acc[i][j]);
      }
      if (ct + 8 < 256) {
        *reinterpret_cast<float4*>(&As[buf ^ 1][lr][lc]) = av;
        *reinterpret_cast<float4*>(&Bs[buf ^ 1][lr][lc]) = bv;
      }
    }
  }

  // epilogue: rows {k0+half*64+ty*4+i}, cols {j0+tx*4, j0+64+tx*4}
  #pragma unroll
  for (int half = 0; half < 2; ++half) {
    #pragma unroll
    for (int i = 0; i < 4; ++i) {
      float* Dp = D + (size_t)(k0 + half * 64 + ty * 4 + i) * ldD + j0;
      *reinterpret_cast<float4*>(Dp + tx * 4)      = *reinterpret_cast<const float4*>(&acc[half * 4 + i][0]);
      *reinterpret_cast<float4*>(Dp + 64 + tx * 4) = *reinterpret_cast<const float4*>(&acc[half * 4 + i][4]);
    }
  }
}

// ---------------- 9-tap DIAGONAL sum + max/argmax, 4 q per thread ----------------
// rel(k,q) = sum over valid delta in {0,+-1,+-63,+-64,+-65} of D[k+delta][q+delta]
// grid: (Wq/1024, KC2, nz); block 256. Chunk = 32 k within one key row (kh uniform).
__global__ __launch_bounds__(256) void reduce_max4(const float* __restrict__ Dbase,
                                                   int ldD, int C0, int Q0,
                                                   const float* __restrict__ kinv,
                                                   float* __restrict__ chunkv,
                                                   int* __restrict__ chunki,
                                                   int n0, long long dstride) {
  __shared__ float sk[KCH];
  const int n = n0 + blockIdx.z;
  const float* D = Dbase + (size_t)blockIdx.z * (size_t)dstride;
  const int k0 = blockIdx.y * KCH;
  const int kh = k0 >> 6;
  const int kwb = k0 & 63;            // 0 or 32
  if (threadIdx.x < KCH) sk[threadIdx.x] = kinv[n * 4096 + k0 + threadIdx.x];
  __syncthreads();

  const int q0 = Q0 + (blockIdx.x * 256 + threadIdx.x) * 4;
  const int qh = q0 >> 6;
  const int qw0 = q0 & 63;
  const bool up = (kh > 0) && (qh > 0);
  const bool dn = (kh < 63) && (qh < 63);
  const bool lf_ok = qw0 > 0;     // lane0's dx=-1 tap column valid
  const bool rt_ok = qw0 < 60;    // lane3's dx=+1 tap column valid

  float b0 = -INFINITY, b1 = -INFINITY, b2 = -INFINITY, b3 = -INFINITY;
  int i0 = k0, i1 = k0, i2 = k0, i3 = k0;
  const float* Dq = D + (q0 - C0);
  const int step = ldD + 1;

  #pragma unroll 4
  for (int kk = 0; kk < KCH; ++kk) {
    const int kw = kwb + kk;
    const float* P = Dq + (size_t)(k0 + kk) * ldD;
    float4 c0 = *reinterpret_cast<const float4*>(P);
    float r0 = c0.x, r1 = c0.y, r2 = c0.z, r3 = c0.w;
    if (up) {
      float4 c = *reinterpret_cast<const float4*>(P - 64 * step);
      r0 += c.x; r1 += c.y; r2 += c.z; r3 += c.w;
    }
    if (dn) {
      float4 c = *reinterpret_cast<const float4*>(P + 64 * step);
      r0 += c.x; r1 += c.y; r2 += c.z; r3 += c.w;
    }
    if (kw > 0) {                       // dx = -1 taps (k and q columns both shift -1)
      f4u a = *reinterpret_cast<const f4u*>(P - step);
      r0 += lf_ok ? a.v[0] : 0.f; r1 += a.v[1]; r2 += a.v[2]; r3 += a.v[3];
      if (up) {
        f4u b = *reinterpret_cast<const f4u*>(P - 65 * step);
        r0 += lf_ok ? b.v[0] : 0.f; r1 += b.v[1]; r2 += b.v[2]; r3 += b.v[3];
      }
      if (dn) {
        f4u b = *reinterpret_cast<const f4u*>(P + 63 * step);
        r0 += lf_ok ? b.v[0] : 0.f; r1 += b.v[1]; r2 += b.v[2]; r3 += b.v[3];
      }
    }
    if (kw < 63) {                      // dx = +1 taps
      f4u a = *reinterpret_cast<const f4u*>(P + step);
      r0 += a.v[0]; r1 += a.v[1]; r2 += a.v[2]; r3 += rt_ok ? a.v[3] : 0.f;
      if (up) {
        f4u b = *reinterpret_cast<const f4u*>(P - 63 * step);
        r0 += b.v[0]; r1 += b.v[1]; r2 += b.v[2]; r3 += rt_ok ? b.v[3] : 0.f;
      }
      if (dn) {
        f4u b = *reinterpret_cast<const f4u*>(P + 65 * step);
        r0 += b.v[0]; r1 += b.v[1]; r2 += b.v[2]; r3 += rt_ok ? b.v[3] : 0.f;
      }
    }
    const float s = sk[kk];
    const int k = k0 + kk;
    float v0 = r0 * s, v1 = r1 * s, v2 = r2 * s, v3 = r3 * s;
    if (v0 > b0) { b0 = v0; i0 = k; }
    if (v1 > b1) { b1 = v1; i1 = k; }
    if (v2 > b2) { b2 = v2; i2 = k; }
    if (v3 > b3) { b3 = v3; i3 = k; }
  }
  const int ob = (n * KC2 + blockIdx.y) * 4096 + q0;
  *reinterpret_cast<float4*>(chunkv + ob) = make_float4(b0, b1, b2, b3);
  *reinterpret_cast<int4*>(chunki + ob) = make_int4(i0, i1, i2, i3);
}

// ---------------- combine chunks: final max/argmax, soft attention out ----------------
__global__ __launch_bounds__(256) void combine_k(const float* __restrict__ chunkv,
                                                 const int* __restrict__ chunki,
                                                 const float* __restrict__ qinv,
                                                 float* __restrict__ out_sa,
                                                 int* __restrict__ maxidx) {
  int t = blockIdx.x * 256 + threadIdx.x;   // 0..8191
  int n = t >> 12, q = t & 4095;
  float best = -INFINITY;
  int bi = 0;
  #pragma unroll 8
  for (int ch = 0; ch < KC2; ++ch) {
    int ii = (n * KC2 + ch) * 4096 + q;
    float v = chunkv[ii];
    int ix = chunki[ii];
    if (v > best) { best = v; bi = ix; }   // ascending chunks + strict > == first-index tie-break
  }
  maxidx[t] = bi;
  out_sa[t] = best * qinv[t];
}

// ---------------- gather + fold textures ----------------
__global__ __launch_bounds__(256) void texture_k(const float* __restrict__ ref,
                                                 const int* __restrict__ maxidx,
                                                 float* __restrict__ outp,
                                                 int sh, int lw, int lh, int lc) {
  int idx = blockIdx.x * 256 + threadIdx.x;
  const int WW = 1 << lw, HH = 1 << lh, CC = 1 << lc;
  const int s = 1 << sh;
  int x = idx & (WW - 1);
  int y = (idx >> lw) & (HH - 1);
  int c = (idx >> (lw + lh)) & (CC - 1);
  int n = idx >> (lw + lh + lc);
  int jh0 = y >> sh, jw0 = x >> sh;
  const int* mi = maxidx + n * 4096;
  float acc = 0.f;
  const float* rb = ref + ((size_t)(n * CC + c) << (lw + lh));
  #pragma unroll
  for (int a = -1; a <= 1; ++a) {
    int jh = jh0 + a;
    if ((unsigned)jh < 64u) {
      #pragma unroll
      for (int b = -1; b <= 1; ++b) {
        int jw = jw0 + b;
        if ((unsigned)jw < 64u) {
          int m = mi[jh * 64 + jw];
          int sy = y + ((m >> 6) - jh) * s;
          int sx = x + ((m & 63) - jw) * s;
          if ((unsigned)sy < (unsigned)HH && (unsigned)sx < (unsigned)WW)
            acc += rb[(sy << lw) + sx];
        }
      }
    }
  }
  outp[idx] = acc * (1.0f / 9.0f);
}

// ---------------- launch ----------------
extern "C" void kernel_launch(void* const* d_in, const int* in_sizes, int n_in,
                              void* d_out, int out_size, void* d_ws, size_t ws_size,
                              hipStream_t stream) {
  const float* lq    = (const float*)d_in[0];
  const float* refdu = (const float*)d_in[1];
  const float* ref0  = (const float*)d_in[2];
  const float* ref1  = (const float*)d_in[3];
  const float* ref2  = (const float*)d_in[4];
  float* out = (float*)d_out;

  // workspace layout (floats/ints, 4B each)
  float* S      = (float*)d_ws;               // 16384
  float* qinv   = S + 16384;                  // 8192
  float* kinv   = qinv + 8192;                // 8192
  int*   maxidx = (int*)(kinv + 8192);        // 8192
  float* chunkv = (float*)(maxidx + 8192);    // 2*KC2*4096 = 1048576
  int*   chunki = (int*)(chunkv + 1048576);   // 1048576
  const size_t aux_bytes = (size_t)(16384 + 8192 + 8192 + 8192 + 1048576 + 1048576) * 4;
  float* D = (float*)((char*)d_ws + aux_bytes);

  size_t avail = (ws_size > aux_bytes) ? (ws_size - aux_bytes) : 0;
  const size_t stripe4096 = (size_t)4096 * 4352 * 4;   // one full-width D, bytes

  // norms
  sumsq_k<<<dim3(16, 2, 2), 256, 0, stream>>>(lq, refdu, S);
  norm_k<<<dim3(64), 256, 0, stream>>>(S, qinv, kinv);

  if (avail >= 2 * stripe4096) {
    // ---- merged path: both batches' full D resident ----
    const int ldD = 4352, C0 = -128;
    const long long dstride = (long long)4096 * 4352;
    gemm_d<<<dim3(32, ldD / 128, 2), 256, 0, stream>>>(refdu, lq, D, ldD, C0, dstride);
    reduce_max4<<<dim3(4, KC2, 2), 256, 0, stream>>>(D, ldD, C0, 0, kinv,
                                                     chunkv, chunki, 0, dstride);
  } else {
    // ---- stripe fallback ----
    int Wq = 1024;
    const int cands[3] = {4096, 2048, 1024};
    for (int i = 0; i < 3; ++i) {
      size_t need = (size_t)4096 * (size_t)(cands[i] + 256) * 4;
      if (need <= avail) { Wq = cands[i]; break; }
    }
    const int ldD = Wq + 256;
    for (int n = 0; n < 2; ++n) {
      const float* A = refdu + (size_t)n * 1048576;
      const float* B = lq    + (size_t)n * 1048576;
      for (int Q0 = 0; Q0 < 4096; Q0 += Wq) {
        int C0 = Q0 - 128;
        gemm_d<<<dim3(32, ldD / 128, 1), 256, 0, stream>>>(A, B, D, ldD, C0, 0);
        reduce_max4<<<dim3(Wq / 1024, KC2, 1), 256, 0, stream>>>(
            D, ldD, C0, Q0, kinv, chunkv, chunki, n, 0);
      }
    }
  }

  // final argmax + soft attention (out[0:8192])
  combine_k<<<dim3(32), 256, 0, stream>>>(chunkv, chunki, qinv, out, maxidx);

  // textures
  texture_k<<<dim3(2097152 / 256), 256, 0, stream>>>(ref0, maxidx, out + 8192,    0, 6, 6, 8);
  texture_k<<<dim3(4194304 / 256), 256, 0, stream>>>(ref1, maxidx, out + 2105344, 1, 7, 7, 7);
  texture_k<<<dim3(8388608 / 256), 256, 0, stream>>>(ref2, maxidx, out + 6299648, 2, 8, 8, 6);
}